// Round 8
// baseline (79.541 us; speedup 1.0000x reference)
//
#include <hip/hip_runtime.h>
#include <math.h>
#include <stdint.h>

#define LOG2E  1.44269504088896340736f
#define LN2    0.69314718055994530942f
#define LOG2PI 1.8378770664093453f

#define NN 2048
#define DD 64

// single-instruction transcendentals (v_exp_f32 / v_log_f32)
__device__ __forceinline__ float fexp2(float x) { return __builtin_amdgcn_exp2f(x); }
__device__ __forceinline__ float flog2(float x) { return __builtin_amdgcn_logf(x); }

// ---------------------------------------------------------------------------
// K1: per-(j,d) factors. a*log2e = z2*p + z*q + r2 with
//   p = -0.5*exp(-lv)*log2e, q = -2*mean*p, r2 = mean^2*p -0.5*(lv+LOG2PI)*log2e
// Outputs: packed[j][d]={p,q,r2,0}; pqT[d][j]={p,q}; zz[i][d]={z^2,z}; r[j]=sum_d r2
// ---------------------------------------------------------------------------
__global__ __launch_bounds__(1024) void k1_precompute(
    const float* __restrict__ z, const float* __restrict__ z_mean,
    const float* __restrict__ z_lv,
    float4* __restrict__ packed, float2* __restrict__ pqT,
    float2* __restrict__ zz, float* __restrict__ r)
{
    __shared__ float aL[64][65], bL[64][65], cL[64][65];
    int tid  = threadIdx.x;
    int lane = tid & 63;     // d in compute phases, j in store phases
    int row  = tid >> 6;     // 0..15
    int jb   = blockIdx.x * 64;

    #pragma unroll
    for (int ppp = 0; ppp < 4; ++ppp) {
        int jl  = ppp * 16 + row;
        int idx = (jb + jl) * DD + lane;
        float mean = z_mean[idx], lv = z_lv[idx];
        float p   = -0.5f * fexp2(-lv * LOG2E) * LOG2E;
        float q   = -2.0f * mean * p;
        float c22 = -0.5f * (lv + LOG2PI) * LOG2E;
        float r2  = fmaf(mean * mean, p, c22);
        packed[idx] = make_float4(p, q, r2, 0.0f);
        aL[jl][lane] = p; bL[jl][lane] = q; cL[jl][lane] = r2;
        float zv = z[idx];
        zz[idx] = make_float2(zv * zv, zv);
    }
    __syncthreads();
    #pragma unroll
    for (int ppp = 0; ppp < 4; ++ppp) {
        int dd = ppp * 16 + row;
        pqT[(size_t)dd * NN + jb + lane] = make_float2(aL[lane][dd], bL[lane][dd]);
    }
    if (tid < 64) {
        float s = 0.0f;
        #pragma unroll
        for (int dd = 0; dd < 64; ++dd) s += cL[tid][dd];
        r[jb + tid] = s;
    }
}

// ---------------------------------------------------------------------------
// K3: sums[jsl][i][d] = sum_{j in 256-slice} 2^{z2*p + z*q + r2} (fixed max 0;
// args <= ~1.2 in log2, underflow-to-0 harmless).
// OCCUPANCY experiment: 256-thr blocks (4 waves), i-tile 8 -> ~52 VGPR so
// 8 blocks/CU = 2048 thr/CU = 100% occupancy. Grid: 256 i-tiles x 8
// j-slices = 2048 blocks. Wave w owns 64 j's; lane = d; stream from L2.
// ---------------------------------------------------------------------------
__global__ __launch_bounds__(256) void k3_perd(
    const float* __restrict__ z, const float4* __restrict__ packed,
    float* __restrict__ sums)
{
    __shared__ float sm[8][4][DD];   // 8 KB
    int tid  = threadIdx.x;
    int lane = tid & 63, w = tid >> 6;   // 4 waves
    int it   = blockIdx.x >> 3;          // 0..255
    int jsl  = blockIdx.x & 7;           // 0..7
    int i0   = it * 8;
    int j0   = jsl * 256 + w * 64;

    float zr[8], z2r[8], s[8];
    #pragma unroll
    for (int k = 0; k < 8; ++k) {
        zr[k]  = z[(i0 + k) * DD + lane];
        z2r[k] = zr[k] * zr[k];
        s[k]   = 0.0f;
    }

    const float4* pk = packed + (size_t)j0 * DD + lane;
    #pragma unroll 4
    for (int jj = 0; jj < 64; ++jj) {
        float4 c = pk[(size_t)jj * DD];   // {p, q, r2, -}
        #pragma unroll
        for (int k = 0; k < 8; ++k) {
            float arg = fmaf(z2r[k], c.x, fmaf(zr[k], c.y, c.z));
            s[k] += fexp2(arg);
        }
    }

    #pragma unroll
    for (int k = 0; k < 8; ++k) sm[k][w][lane] = s[k];
    __syncthreads();

    #pragma unroll
    for (int k = w; k < 8; k += 4) {
        float tot = sm[k][0][lane] + sm[k][1][lane] + sm[k][2][lane] + sm[k][3][lane];
        sums[((size_t)jsl * NN + i0 + k) * DD + lane] = tot;
    }
}

// ---------------------------------------------------------------------------
// K2: acc[i] = sum_d z2*p + z*q; fixed-max partial sum:
//   part = sum_j 2^{acc + r[j] + 64}  (+64 shift keeps terms above the
//   denormal floor; negligible terms underflow harmlessly).
// 256-thr blocks, i-tile 16, 24.5 KB LDS. Grid: 128 i-tiles x 8 j-blocks
// = 1024 blocks (4/CU). zz tile via broadcast float4 ds_reads; pq coalesced.
// ---------------------------------------------------------------------------
__global__ __launch_bounds__(256) void k2_logqz(
    const float2* __restrict__ zz, const float2* __restrict__ pqT,
    const float* __restrict__ r, float* __restrict__ k2part)
{
    __shared__ float2 zzL[DD][17];   // padded, 8.5 KB
    __shared__ float  pb[16][256];   // 16 KB
    int tid = threadIdx.x;
    int it  = blockIdx.x >> 3;
    int jb  = blockIdx.x & 7;
    int i0  = it * 16;
    int j   = jb * 256 + tid;

    #pragma unroll
    for (int t2 = 0; t2 < 4; ++t2) {
        int idx = t2 * 256 + tid;        // 16 i x 64 d
        int i = idx >> 6, d = idx & 63;
        zzL[d][i] = zz[(size_t)(i0 + i) * DD + d];
    }
    __syncthreads();

    float acc[16];
    #pragma unroll
    for (int i = 0; i < 16; ++i) acc[i] = 0.0f;

    #pragma unroll 2
    for (int d = 0; d < DD; ++d) {
        float2 pq = pqT[(size_t)d * NN + j];   // coalesced
        #pragma unroll
        for (int ip = 0; ip < 8; ++ip) {
            float4 t = *(const float4*)&zzL[d][2 * ip];   // broadcast {z2,z,z2,z}
            acc[2 * ip]     = fmaf(t.x, pq.x, fmaf(t.y, pq.y, acc[2 * ip]));
            acc[2 * ip + 1] = fmaf(t.z, pq.x, fmaf(t.w, pq.y, acc[2 * ip + 1]));
        }
    }

    float rj = r[j] + 64.0f;   // +64 log2: underflow guard
    #pragma unroll
    for (int i = 0; i < 16; ++i) pb[i][tid] = fexp2(acc[i] + rj);
    __syncthreads();

    int w = tid >> 6, lane = tid & 63;
    #pragma unroll
    for (int ii = w; ii < 16; ii += 4) {
        float ss = pb[ii][lane] + pb[ii][lane + 64] + pb[ii][lane + 128] + pb[ii][lane + 192];
        #pragma unroll
        for (int off = 32; off; off >>= 1) ss += __shfl_xor(ss, off, 64);
        if (lane == 0) k2part[(size_t)jb * NN + i0 + ii] = ss;
    }
}

// ---------------------------------------------------------------------------
// K5: diff[i] = ln2*sum_d log2(sum_{8 jsl} sums) - ln2*(log2(sum_jb part)-64)
// Block 256 = 4 i's (wave per i, lane = d). Grid 512.
// ---------------------------------------------------------------------------
__global__ __launch_bounds__(256) void k5_merge(
    const float* __restrict__ sums, const float* __restrict__ k2part,
    float* __restrict__ diff)
{
    int lane = threadIdx.x & 63, w = threadIdx.x >> 6;
    int i = blockIdx.x * 4 + w;

    float tot = 0.0f;
    #pragma unroll
    for (int q = 0; q < 8; ++q) tot += sums[((size_t)q * NN + i) * DD + lane];
    float t = flog2(tot);
    #pragma unroll
    for (int off = 32; off; off >>= 1) t += __shfl_xor(t, off, 64);

    if (lane == 0) {
        float ss = 0.0f;
        #pragma unroll
        for (int q = 0; q < 8; ++q) ss += k2part[(size_t)q * NN + i];
        diff[i] = LN2 * t - LN2 * (flog2(ss) - 64.0f);
    }
}

// ---------------------------------------------------------------------------
// K6: out = mean_i diff[i]
// ---------------------------------------------------------------------------
__global__ __launch_bounds__(256) void k6_final(
    const float* __restrict__ diff, float* __restrict__ out)
{
    __shared__ float red[256];
    int tid = threadIdx.x;
    float t = 0.0f;
    for (int k = tid; k < NN; k += 256) t += diff[k];
    red[tid] = t;
    __syncthreads();
    #pragma unroll
    for (int off = 128; off; off >>= 1) {
        if (tid < off) red[tid] += red[tid + off];
        __syncthreads();
    }
    if (tid == 0) out[0] = red[0] * (1.0f / (float)NN);
}

extern "C" void kernel_launch(void* const* d_in, const int* in_sizes, int n_in,
                              void* d_out, int out_size, void* d_ws, size_t ws_size,
                              hipStream_t stream)
{
    const float* z      = (const float*)d_in[0];
    const float* z_mean = (const float*)d_in[1];
    const float* z_lv   = (const float*)d_in[2];
    float* out = (float*)d_out;

    float* ws = (float*)d_ws;
    float4* packed = (float4*)ws;                            // 2 MB
    float*  base   = ws + (size_t)NN * DD * 4;
    float2* pqT    = (float2*)base;                          // 1 MB
    float2* zz     = (float2*)(base + (size_t)NN * DD * 2);  // 1 MB
    float*  r      = base + (size_t)NN * DD * 4;             // 8 KB
    float*  sums   = r + NN;                                 // 8*N*D = 4 MB
    float*  k2part = sums + (size_t)8 * NN * DD;             // 64 KB
    float*  diff   = k2part + (size_t)8 * NN;                // 8 KB

    k1_precompute<<<NN / 64, 1024, 0, stream>>>(z, z_mean, z_lv, packed, pqT, zz, r);
    k3_perd<<<2048, 256, 0, stream>>>(z, packed, sums);
    k2_logqz<<<1024, 256, 0, stream>>>(zz, pqT, r, k2part);
    k5_merge<<<NN / 4, 256, 0, stream>>>(sums, k2part, diff);
    k6_final<<<1, 256, 0, stream>>>(diff, out);
}

// Round 9
// 74.051 us; speedup vs baseline: 1.0741x; 1.0741x over previous
//
#include <hip/hip_runtime.h>
#include <math.h>
#include <stdint.h>

#define LOG2E  1.44269504088896340736f
#define LN2    0.69314718055994530942f
#define LOG2PI 1.8378770664093453f

#define NN 2048
#define DD 64

// Schraudolph constants (scale 2^16, window [2^23, 2^24), x in [-120, +8)):
//   y = x*2^16 + (120*2^16 + 2^23)         -> BIAS_F folded into r2''
//   exp2(x) ~= as_float((bits(y) << 7) + KBIT)
//   KBIT = (7 - sigma)*2^23 - (0x4B000000 << 7 mod 2^32), sigma = 0.035
//   error factor in [0.965, 1.0355] -> worst-case output err ~2.3 nats << 9.8
#define BIAS_F 16252928.0f
#define KBIT   2205910303u
#define CLAMP_LO 8388608.0f   // y floor (x = -120)

// single-instruction transcendentals (for the tiny K1/K2/K5 usage)
__device__ __forceinline__ float fexp2(float x) { return __builtin_amdgcn_exp2f(x); }
__device__ __forceinline__ float flog2(float x) { return __builtin_amdgcn_logf(x); }

// ---------------------------------------------------------------------------
// K1: per-(j,d) factors. a*log2e = z2*p + z*q + r2 with
//   p = -0.5*exp(-lv)*log2e, q = -2*mean*p, r2 = mean^2*p -0.5*(lv+LOG2PI)*log2e
// Outputs:
//   pq3[j*64+d] = {p*2^16, q*2^16}   (K3, Schraudolph-scaled)
//   r2s[j*64+d] = r2*2^16 + BIAS_F   (K3)
//   pqT[d][j]   = {p, q}             (K2, unscaled, coalesced in j)
//   zz[i][d]    = {z^2, z}           (K2)
//   r[j]        = sum_d r2           (K2, unscaled)
// ---------------------------------------------------------------------------
__global__ __launch_bounds__(1024) void k1_precompute(
    const float* __restrict__ z, const float* __restrict__ z_mean,
    const float* __restrict__ z_lv,
    float2* __restrict__ pq3, float* __restrict__ r2s,
    float2* __restrict__ pqT, float2* __restrict__ zz, float* __restrict__ r)
{
    __shared__ float aL[64][65], bL[64][65], cL[64][65];
    int tid  = threadIdx.x;
    int lane = tid & 63;     // d in compute phases, j in store phases
    int row  = tid >> 6;     // 0..15
    int jb   = blockIdx.x * 64;

    #pragma unroll
    for (int ppp = 0; ppp < 4; ++ppp) {
        int jl  = ppp * 16 + row;
        int idx = (jb + jl) * DD + lane;
        float mean = z_mean[idx], lv = z_lv[idx];
        float p   = -0.5f * fexp2(-lv * LOG2E) * LOG2E;
        float q   = -2.0f * mean * p;
        float c22 = -0.5f * (lv + LOG2PI) * LOG2E;
        float r2  = fmaf(mean * mean, p, c22);
        pq3[idx] = make_float2(p * 65536.0f, q * 65536.0f);
        r2s[idx] = fmaf(r2, 65536.0f, BIAS_F);
        aL[jl][lane] = p; bL[jl][lane] = q; cL[jl][lane] = r2;
        float zv = z[idx];
        zz[idx] = make_float2(zv * zv, zv);
    }
    __syncthreads();
    #pragma unroll
    for (int ppp = 0; ppp < 4; ++ppp) {
        int dd = ppp * 16 + row;
        pqT[(size_t)dd * NN + jb + lane] = make_float2(aL[lane][dd], bL[lane][dd]);
    }
    if (tid < 64) {
        float s = 0.0f;
        #pragma unroll
        for (int dd = 0; dd < 64; ++dd) s += cL[tid][dd];
        r[jb + tid] = s;
    }
}

// ---------------------------------------------------------------------------
// K3: sums[jsl][i][d] = sum_{j in 256-slice} exp2(z2*p + z*q + r2),
// exp2 via Schraudolph bit-trick: 5 full-rate VALU ops per element, ZERO
// trans-pipe ops (the r4-r8 pedestal fit says v_exp_f32 blocks the shared
// issue port ~13cy; this is the discriminating experiment).
// Block: 512 thr = 8 waves; i-tile 8; wave owns 32 j's; lane = d.
// Grid: 256 i-tiles x 8 j-slices = 2048 blocks (~45 VGPR, 16 KB LDS).
// ---------------------------------------------------------------------------
__global__ __launch_bounds__(512) void k3_perd(
    const float* __restrict__ z, const float2* __restrict__ pq3,
    const float* __restrict__ r2s, float* __restrict__ sums)
{
    __shared__ float sm[8][8][DD];   // 16 KB
    int tid  = threadIdx.x;
    int lane = tid & 63, w = tid >> 6;   // 8 waves
    int it   = blockIdx.x >> 3;          // 0..255
    int jsl  = blockIdx.x & 7;           // 0..7
    int i0   = it * 8;
    int j0   = jsl * 256 + w * 32;

    float zr[8], z2r[8], s[8];
    #pragma unroll
    for (int k = 0; k < 8; ++k) {
        zr[k]  = z[(i0 + k) * DD + lane];
        z2r[k] = zr[k] * zr[k];
        s[k]   = 0.0f;
    }

    const float2* pp = pq3 + (size_t)j0 * DD + lane;
    const float*  rr = r2s + (size_t)j0 * DD + lane;
    #pragma unroll 4
    for (int jj = 0; jj < 32; ++jj) {
        float2 c  = pp[(size_t)jj * DD];   // {p', q'}
        float  rc = rr[(size_t)jj * DD];   // r2'' (bias folded)
        #pragma unroll
        for (int k = 0; k < 8; ++k) {
            float t = fmaf(z2r[k], c.x, fmaf(zr[k], c.y, rc));
            t = fmaxf(t, CLAMP_LO);
            s[k] += __uint_as_float((__float_as_uint(t) << 7) + KBIT);
        }
    }

    #pragma unroll
    for (int k = 0; k < 8; ++k) sm[k][w][lane] = s[k];
    __syncthreads();

    // wave w finishes row i0+w
    float tot = 0.0f;
    #pragma unroll
    for (int w2 = 0; w2 < 8; ++w2) tot += sm[w][w2][lane];
    sums[((size_t)jsl * NN + i0 + w) * DD + lane] = tot;
}

// ---------------------------------------------------------------------------
// K2: acc[i] = sum_d z2*p + z*q; fixed-max partial sum:
//   part = sum_j 2^{acc + r[j] + 64}  (+64 shift keeps terms above the
//   denormal floor; negligible terms underflow harmlessly).
// 256-thr blocks, i-tile 16, 24.5 KB LDS. Grid: 128 i-tiles x 8 j-blocks.
// (unchanged from r8 — known-good, ~10 us, ds-broadcast bound)
// ---------------------------------------------------------------------------
__global__ __launch_bounds__(256) void k2_logqz(
    const float2* __restrict__ zz, const float2* __restrict__ pqT,
    const float* __restrict__ r, float* __restrict__ k2part)
{
    __shared__ float2 zzL[DD][17];   // padded, 8.5 KB
    __shared__ float  pb[16][256];   // 16 KB
    int tid = threadIdx.x;
    int it  = blockIdx.x >> 3;
    int jb  = blockIdx.x & 7;
    int i0  = it * 16;
    int j   = jb * 256 + tid;

    #pragma unroll
    for (int t2 = 0; t2 < 4; ++t2) {
        int idx = t2 * 256 + tid;        // 16 i x 64 d
        int i = idx >> 6, d = idx & 63;
        zzL[d][i] = zz[(size_t)(i0 + i) * DD + d];
    }
    __syncthreads();

    float acc[16];
    #pragma unroll
    for (int i = 0; i < 16; ++i) acc[i] = 0.0f;

    #pragma unroll 2
    for (int d = 0; d < DD; ++d) {
        float2 pq = pqT[(size_t)d * NN + j];   // coalesced
        #pragma unroll
        for (int ip = 0; ip < 8; ++ip) {
            float4 t = *(const float4*)&zzL[d][2 * ip];   // broadcast {z2,z,z2,z}
            acc[2 * ip]     = fmaf(t.x, pq.x, fmaf(t.y, pq.y, acc[2 * ip]));
            acc[2 * ip + 1] = fmaf(t.z, pq.x, fmaf(t.w, pq.y, acc[2 * ip + 1]));
        }
    }

    float rj = r[j] + 64.0f;   // +64 log2: underflow guard
    #pragma unroll
    for (int i = 0; i < 16; ++i) pb[i][tid] = fexp2(acc[i] + rj);
    __syncthreads();

    int w = tid >> 6, lane = tid & 63;
    #pragma unroll
    for (int ii = w; ii < 16; ii += 4) {
        float ss = pb[ii][lane] + pb[ii][lane + 64] + pb[ii][lane + 128] + pb[ii][lane + 192];
        #pragma unroll
        for (int off = 32; off; off >>= 1) ss += __shfl_xor(ss, off, 64);
        if (lane == 0) k2part[(size_t)jb * NN + i0 + ii] = ss;
    }
}

// ---------------------------------------------------------------------------
// K5: diff[i] = ln2*sum_d log2(sum_{8 jsl} sums) - ln2*(log2(sum_jb part)-64)
// Block 256 = 4 i's (wave per i, lane = d). Grid 512.
// ---------------------------------------------------------------------------
__global__ __launch_bounds__(256) void k5_merge(
    const float* __restrict__ sums, const float* __restrict__ k2part,
    float* __restrict__ diff)
{
    int lane = threadIdx.x & 63, w = threadIdx.x >> 6;
    int i = blockIdx.x * 4 + w;

    float tot = 0.0f;
    #pragma unroll
    for (int q = 0; q < 8; ++q) tot += sums[((size_t)q * NN + i) * DD + lane];
    float t = flog2(tot);
    #pragma unroll
    for (int off = 32; off; off >>= 1) t += __shfl_xor(t, off, 64);

    if (lane == 0) {
        float ss = 0.0f;
        #pragma unroll
        for (int q = 0; q < 8; ++q) ss += k2part[(size_t)q * NN + i];
        diff[i] = LN2 * t - LN2 * (flog2(ss) - 64.0f);
    }
}

// ---------------------------------------------------------------------------
// K6: out = mean_i diff[i]
// ---------------------------------------------------------------------------
__global__ __launch_bounds__(256) void k6_final(
    const float* __restrict__ diff, float* __restrict__ out)
{
    __shared__ float red[256];
    int tid = threadIdx.x;
    float t = 0.0f;
    for (int k = tid; k < NN; k += 256) t += diff[k];
    red[tid] = t;
    __syncthreads();
    #pragma unroll
    for (int off = 128; off; off >>= 1) {
        if (tid < off) red[tid] += red[tid + off];
        __syncthreads();
    }
    if (tid == 0) out[0] = red[0] * (1.0f / (float)NN);
}

extern "C" void kernel_launch(void* const* d_in, const int* in_sizes, int n_in,
                              void* d_out, int out_size, void* d_ws, size_t ws_size,
                              hipStream_t stream)
{
    const float* z      = (const float*)d_in[0];
    const float* z_mean = (const float*)d_in[1];
    const float* z_lv   = (const float*)d_in[2];
    float* out = (float*)d_out;

    float* ws = (float*)d_ws;
    float2* pq3 = (float2*)ws;                               // N*D f2 (1 MB)
    float*  r2s = ws + (size_t)NN * DD * 2;                  // N*D    (0.5 MB)
    float2* pqT = (float2*)(ws + (size_t)NN * DD * 3);       // N*D f2 (1 MB)
    float2* zz  = (float2*)(ws + (size_t)NN * DD * 5);       // N*D f2 (1 MB)
    float*  r   = ws + (size_t)NN * DD * 7;                  // N
    float*  sums   = r + NN;                                 // 8*N*D (4 MB)
    float*  k2part = sums + (size_t)8 * NN * DD;             // 8*N
    float*  diff   = k2part + (size_t)8 * NN;                // N

    k1_precompute<<<NN / 64, 1024, 0, stream>>>(z, z_mean, z_lv, pq3, r2s, pqT, zz, r);
    k3_perd<<<2048, 512, 0, stream>>>(z, pq3, r2s, sums);
    k2_logqz<<<1024, 256, 0, stream>>>(zz, pqT, r, k2part);
    k5_merge<<<NN / 4, 256, 0, stream>>>(sums, k2part, diff);
    k6_final<<<1, 256, 0, stream>>>(diff, out);
}